// Round 1
// baseline (306.279 us; speedup 1.0000x reference)
//
#include <hip/hip_runtime.h>
#include <math.h>

#ifndef __has_builtin
#define __has_builtin(x) 0
#endif

__device__ __forceinline__ float fast_sqrt(float x){
#if __has_builtin(__builtin_amdgcn_sqrtf)
    return __builtin_amdgcn_sqrtf(x);
#else
    return sqrtf(x);
#endif
}
__device__ __forceinline__ float fast_rcp(float x){
#if __has_builtin(__builtin_amdgcn_rcpf)
    return __builtin_amdgcn_rcpf(x);
#else
    return 1.0f/x;
#endif
}

namespace {
constexpr int TT = 256;     // T
constexpr int BB = 16384;   // B
}

__global__ __launch_bounds__(64)
void ukf_kernel(const float* __restrict__ yg, const float* __restrict__ ug,
                const float* __restrict__ z0g, const float* __restrict__ P0g,
                float* __restrict__ outg)
{
    const int b = blockIdx.x * 64 + threadIdx.x;
    if (b >= BB) return;

    constexpr float DT  = 0.05f, CD = 0.25f, AP = 0.1f, AV = 0.1f;
    constexpr float JIT = 1e-6f, SQC = 1.6f;
    // LAM = 0.64*4-4 = -1.44 ; CUT = 2.56 ; wm0 = -0.5625 ; wi = 0.1953125
    // wc0 = wm0 + (1 - 0.64 + 2.0) = 1.7975
    constexpr float WM0 = -0.5625f, WI = 0.1953125f, WC0 = 1.7975f;
    constexpr float Rd  = 0.0025f;                  // R diag (0.05^2)
    const float Qd[4] = {1e-5f, 1e-4f, 1e-6f, 1e-6f};

    // ---- load state ----
    float z[4];
    #pragma unroll
    for (int i=0;i<4;i++) z[i] = z0g[b*4+i];
    float P[4][4];
    #pragma unroll
    for (int i=0;i<4;i++)
        #pragma unroll
        for (int j=0;j<4;j++)
            P[i][j] = 0.5f*(P0g[b*16+i*4+j] + P0g[b*16+j*4+i]);  // _sym

    const float* yb = yg  + (size_t)b*TT*2;
    const float* ub = ug  + (size_t)b*TT;
    float*       ob = outg + (size_t)b*TT*4;

    float Xs[9][4];
    float zp[4], Pp[4][4];

    for (int t = 0; t < TT; ++t) {
        // ---- cholesky of P + JIT*I (P kept symmetric) ----
        float l00 = fast_sqrt(P[0][0] + JIT);
        float i0  = fast_rcp(l00);
        float l10 = P[1][0]*i0, l20 = P[2][0]*i0, l30 = P[3][0]*i0;
        float l11 = fast_sqrt(P[1][1] + JIT - l10*l10);
        float i1  = fast_rcp(l11);
        float l21 = (P[2][1]-l20*l10)*i1, l31 = (P[3][1]-l30*l10)*i1;
        float l22 = fast_sqrt(P[2][2] + JIT - l20*l20 - l21*l21);
        float i2  = fast_rcp(l22);
        float l32 = (P[3][2]-l30*l20-l31*l21)*i2;
        float l33 = fast_sqrt(P[3][3] + JIT - l30*l30 - l31*l31 - l32*l32);
        const float L[4][4] = {{l00,0.f,0.f,0.f},{l10,l11,0.f,0.f},
                               {l20,l21,l22,0.f},{l30,l31,l32,l33}};

        // ---- sigma points: X0=z, X_{1+i}=z + sqrt(c)*L[:,i], X_{5+i}=z - ... ----
        #pragma unroll
        for (int j=0;j<4;j++) Xs[0][j] = z[j];
        #pragma unroll
        for (int i=0;i<4;i++)
            #pragma unroll
            for (int j=0;j<4;j++){
                float a = SQC * L[j][i];
                Xs[1+i][j] = z[j] + a;
                Xs[5+i][j] = z[j] - a;
            }

        if (t == 0) {
            // first update uses z0 / P0 directly as the prediction
            #pragma unroll
            for (int i=0;i<4;i++){
                zp[i] = z[i];
                #pragma unroll
                for (int j=0;j<4;j++) Pp[i][j] = P[i][j];
            }
        } else {
            // ---- dynamics on sigma points ----
            float uu = ub[t-1];
            #pragma unroll
            for (int s=0;s<9;s++){
                float p = Xs[s][0], v = Xs[s][1], k = Xs[s][2], al = Xs[s][3];
                float p2  = fmaf(DT, v, p);
                float acc = fmaf(-CD, v, uu) - k*p - al*(p*p*p);
                float v2  = fmaf(DT, acc, v);
                Xs[s][0] = p2; Xs[s][1] = v2;
            }
            // ---- predicted mean ----
            #pragma unroll
            for (int i=0;i<4;i++){
                float a = WM0 * Xs[0][i];
                #pragma unroll
                for (int s=1;s<9;s++) a = fmaf(WI, Xs[s][i], a);
                zp[i] = a;
            }
            // ---- predicted covariance ----
            float acc[4][4];
            {
                float d0[4];
                #pragma unroll
                for (int i=0;i<4;i++) d0[i] = Xs[0][i] - zp[i];
                #pragma unroll
                for (int i=0;i<4;i++)
                    #pragma unroll
                    for (int j=i;j<4;j++)
                        acc[i][j] = WC0 * d0[i] * d0[j];
            }
            #pragma unroll
            for (int s=1;s<9;s++){
                float d[4];
                #pragma unroll
                for (int i=0;i<4;i++) d[i] = Xs[s][i] - zp[i];
                #pragma unroll
                for (int i=0;i<4;i++)
                    #pragma unroll
                    for (int j=i;j<4;j++)
                        acc[i][j] = fmaf(WI*d[i], d[j], acc[i][j]);
            }
            #pragma unroll
            for (int i=0;i<4;i++)
                #pragma unroll
                for (int j=i;j<4;j++){
                    float v = acc[i][j];
                    if (i==j) v += Qd[i] + JIT;
                    Pp[i][j] = v; Pp[j][i] = v;
                }
        }

        // ============ measurement update ============
        float2 yy = *reinterpret_cast<const float2*>(yb + 2*t);

        float Y[9][2];
        #pragma unroll
        for (int s=0;s<9;s++){
            float p = Xs[s][0], v = Xs[s][1];
            Y[s][0] = fmaf(AP*p, p*p, p);
            Y[s][1] = fmaf(AV*v, v*v, v);
        }
        float yp0 = WM0*Y[0][0], yp1 = WM0*Y[0][1];
        #pragma unroll
        for (int s=1;s<9;s++){ yp0 = fmaf(WI, Y[s][0], yp0); yp1 = fmaf(WI, Y[s][1], yp1); }

        float s00=0.f, s01=0.f, s11=0.f;
        float pz[4][2] = {{0.f,0.f},{0.f,0.f},{0.f,0.f},{0.f,0.f}};
        #pragma unroll
        for (int s=0;s<9;s++){
            const float w = (s==0) ? WC0 : WI;
            float d0 = Y[s][0]-yp0, d1 = Y[s][1]-yp1;
            s00 = fmaf(w*d0, d0, s00);
            s01 = fmaf(w*d0, d1, s01);
            s11 = fmaf(w*d1, d1, s11);
            #pragma unroll
            for (int i=0;i<4;i++){
                float dx = Xs[s][i]-zp[i];
                pz[i][0] = fmaf(w*dx, d0, pz[i][0]);
                pz[i][1] = fmaf(w*dx, d1, pz[i][1]);
            }
        }
        // S = sym(S) + R + JIT*I   (single jitter, used for P_post)
        s00 += Rd + JIT;
        s11 += Rd + JIT;

        // Kalman gain via chol of (S + JIT*I)  (reference double-jitters here)
        float g00 = s00 + JIT, g11 = s11 + JIT;
        float c00 = fast_sqrt(g00);
        float ci0 = fast_rcp(c00);
        float c10 = s01 * ci0;
        float c11 = fast_sqrt(g11 - c10*c10);
        float ci1 = fast_rcp(c11);
        float K[4][2];
        #pragma unroll
        for (int i=0;i<4;i++){
            float q0 = pz[i][0]*ci0;
            float q1 = (pz[i][1] - c10*q0)*ci1;
            float x1 = q1*ci1;
            float x0 = (q0 - c10*x1)*ci0;
            K[i][0]=x0; K[i][1]=x1;
        }

        float nu0 = yy.x - yp0, nu1 = yy.y - yp1;
        #pragma unroll
        for (int i=0;i<4;i++)
            z[i] = zp[i] + K[i][0]*nu0 + K[i][1]*nu1;

        // P_post = Pp - K Pzy^T - Pzy K^T + K S K^T  (+ JIT*I, symmetric)
        float KS[4][2];
        #pragma unroll
        for (int i=0;i<4;i++){
            KS[i][0] = K[i][0]*s00 + K[i][1]*s01;
            KS[i][1] = K[i][0]*s01 + K[i][1]*s11;
        }
        #pragma unroll
        for (int i=0;i<4;i++)
            #pragma unroll
            for (int j=i;j<4;j++){
                float mij = K[i][0]*pz[j][0] + K[i][1]*pz[j][1];
                float mji = K[j][0]*pz[i][0] + K[j][1]*pz[i][1];
                float ksk = KS[i][0]*K[j][0] + KS[i][1]*K[j][1];
                float v = Pp[i][j] - mij - mji + ksk;
                if (i==j) v += JIT;
                P[i][j] = v; P[j][i] = v;
            }

        // ---- store posterior mean ----
        float4 zz = make_float4(z[0], z[1], z[2], z[3]);
        *reinterpret_cast<float4*>(ob + 4*t) = zz;
    }
}

extern "C" void kernel_launch(void* const* d_in, const int* in_sizes, int n_in,
                              void* d_out, int out_size, void* d_ws, size_t ws_size,
                              hipStream_t stream) {
    const float* y  = (const float*)d_in[0];   // (B,T,NY)
    const float* u  = (const float*)d_in[1];   // (B,T)
    const float* z0 = (const float*)d_in[2];   // (B,N)
    const float* P0 = (const float*)d_in[3];   // (B,N,N)
    float* out = (float*)d_out;                // (B,T,N)

    dim3 grid(BB / 64), block(64);
    ukf_kernel<<<grid, block, 0, stream>>>(y, u, z0, P0, out);
}

// Round 2
// 189.972 us; speedup vs baseline: 1.6122x; 1.6122x over previous
//
#include <hip/hip_runtime.h>
#include <math.h>

#ifndef __has_builtin
#define __has_builtin(x) 0
#endif

__device__ __forceinline__ float fsqrt(float x){
#if __has_builtin(__builtin_amdgcn_sqrtf)
    return __builtin_amdgcn_sqrtf(x);
#else
    return sqrtf(x);
#endif
}
__device__ __forceinline__ float frsqrt(float x){
#if __has_builtin(__builtin_amdgcn_rsqf)
    return __builtin_amdgcn_rsqf(x);
#else
    return 1.0f/sqrtf(x);
#endif
}
__device__ __forceinline__ float frcp(float x){
#if __has_builtin(__builtin_amdgcn_rcpf)
    return __builtin_amdgcn_rcpf(x);
#else
    return 1.0f/x;
#endif
}

namespace {
constexpr int TT = 256;
constexpr int BB = 16384;
}

__global__ __launch_bounds__(64)
void ukf_kernel(const float* __restrict__ yg, const float* __restrict__ ug,
                const float* __restrict__ z0g, const float* __restrict__ P0g,
                float* __restrict__ outg)
{
    constexpr float DT  = 0.05f, CD = 0.25f, AP = 0.1f, AV = 0.1f;
    constexpr float JIT = 1e-6f;
    constexpr float CUT = 2.56f;          // N + LAM
    constexpr float CJ  = CUT*JIT;
    constexpr float WM0 = -0.5625f, WI = 0.1953125f, WC0 = 1.7975f;
    constexpr float WA  = WC0 + 4.0f*WI;  // 2.57875  (center + 4 degenerate points, cov weight)
    constexpr float WB  = WM0 + 4.0f*WI;  // 0.21875  (mean weight of center-equal points)

    const int b = blockIdx.x*64 + threadIdx.x;

    // ---- load state (P symmetrized, upper triangle kept) ----
    float z0v = z0g[b*4+0], z1v = z0g[b*4+1], z2v = z0g[b*4+2], z3v = z0g[b*4+3];
    const float* Pb = P0g + (size_t)b*16;
    float P00 = Pb[0];
    float P01 = 0.5f*(Pb[1]+Pb[4]);
    float P02 = 0.5f*(Pb[2]+Pb[8]);
    float P03 = 0.5f*(Pb[3]+Pb[12]);
    float P11 = Pb[5];
    float P12 = 0.5f*(Pb[6]+Pb[9]);
    float P13 = 0.5f*(Pb[7]+Pb[13]);
    float P22 = Pb[10];
    float P23 = 0.5f*(Pb[11]+Pb[14]);
    float P33 = Pb[15];

    const float* yb = yg + (size_t)b*TT*2;
    const float* ub = ug + (size_t)b*TT;
    float*       ob = outg + (size_t)b*TT*4;

    // ---- software prefetch pipeline (1 step ahead) ----
    float2 ycur = *reinterpret_cast<const float2*>(yb);
    float2 ynext = *reinterpret_cast<const float2*>(yb + 2);
    float  ucur = 0.0f;            // unused at t=0
    float  unext = ub[0];

    #pragma unroll 1
    for (int t = 0; t < TT; ++t) {
        const bool first = (t == 0);
        const float yv0 = ycur.x, yv1 = ycur.y;

        // ===== G = chol(CUT*(P + JIT*I))  (sigma spread matrix, sqrt(c) folded in) =====
        float a00 = fmaf(CUT, P00, CJ);
        float r0  = frsqrt(a00);
        float g00 = a00*r0;
        float g10 = (CUT*P01)*r0;
        float g20 = (CUT*P02)*r0;
        float g30 = (CUT*P03)*r0;
        float a11 = fmaf(CUT, P11, CJ) - g10*g10;
        float r1  = frsqrt(a11);
        float g11 = a11*r1;
        float g21 = (CUT*P12 - g20*g10)*r1;
        float g31 = (CUT*P13 - g30*g10)*r1;
        float a22 = (fmaf(CUT, P22, CJ) - g20*g20) - g21*g21;
        float r2  = frsqrt(a22);
        float g22 = a22*r2;
        float g32 = ((CUT*P23 - g30*g20) - g31*g21)*r2;
        float a33 = ((fmaf(CUT, P33, CJ) - g30*g30) - g31*g31) - g32*g32;
        float g33 = fsqrt(a33);

        // ===== propagated sigma points, comps 0,1 only =====
        // cols 2,3 of G are zero in comps 0,1 -> those 4 points share the center's (p,v)
        // except for a v-shift from (k,al) perturbation (cols 2,3).
        float X00, X01;
        float Xp0a, Xp0b, Xm0a, Xm0b;                    // comp0: cols 0,1 (cols 2,3 == X00)
        float Xp1_0,Xp1_1,Xp1_2,Xp1_3, Xm1_0,Xm1_1,Xm1_2,Xm1_3;  // comp1: all 4 cols
        float zp0, zp1;
        float B00,B01,B02,B03,B11,B12,B13,B22,B23,B33;   // P_pred

        if (first) {
            X00 = z0v; X01 = z1v;
            Xp0a = z0v + g00; Xm0a = z0v - g00;
            Xp0b = z0v;       Xm0b = z0v;
            Xp1_0 = z1v + g10; Xm1_0 = z1v - g10;
            Xp1_1 = z1v + g11; Xm1_1 = z1v - g11;
            Xp1_2 = z1v; Xm1_2 = z1v;
            Xp1_3 = z1v; Xm1_3 = z1v;
            zp0 = z0v; zp1 = z1v;
        } else {
            // center dynamics
            float t0c = z0v*z0v;
            float zc  = t0c*z0v;                          // p^3 at center
            X00 = fmaf(DT, z1v, z0v);
            float ac = fmaf(-CD, z1v, ucur);
            ac = fmaf(-z2v, z0v, ac);
            ac = fmaf(-z3v, zc, ac);
            X01 = fmaf(DT, ac, z1v);
            // col0 (all comps perturbed)
            float pp = z0v+g00, pm = z0v-g00;
            float vp = z1v+g10, vm = z1v-g10;
            float kp = z2v+g20, km = z2v-g20;
            float ap = z3v+g30, am = z3v-g30;
            Xp0a = fmaf(DT, vp, pp); Xm0a = fmaf(DT, vm, pm);
            float cp = (pp*pp)*pp, cm = (pm*pm)*pm;
            float acp = fmaf(-CD, vp, ucur); acp = fmaf(-kp, pp, acp); acp = fmaf(-ap, cp, acp);
            Xp1_0 = fmaf(DT, acp, vp);
            float acm = fmaf(-CD, vm, ucur); acm = fmaf(-km, pm, acm); acm = fmaf(-am, cm, acm);
            Xm1_0 = fmaf(DT, acm, vm);
            // col1 (p unchanged = z0)
            float vp1 = z1v+g11, vm1 = z1v-g11;
            float kp1 = z2v+g21, km1 = z2v-g21;
            float ap1 = z3v+g31, am1 = z3v-g31;
            Xp0b = fmaf(DT, vp1, z0v); Xm0b = fmaf(DT, vm1, z0v);
            float acp1 = fmaf(-CD, vp1, ucur); acp1 = fmaf(-kp1, z0v, acp1); acp1 = fmaf(-ap1, zc, acp1);
            Xp1_1 = fmaf(DT, acp1, vp1);
            float acm1 = fmaf(-CD, vm1, ucur); acm1 = fmaf(-km1, z0v, acm1); acm1 = fmaf(-am1, zc, acm1);
            Xm1_1 = fmaf(DT, acm1, vm1);
            // col2: only (k,al) perturbed -> v2 = X01 -/+ DT*(g22*p + g32*p^3)
            float h2 = fmaf(g32, zc, g22*z0v);
            Xp1_2 = fmaf(-DT, h2, X01); Xm1_2 = fmaf(DT, h2, X01);
            // col3: only al perturbed
            float h3 = g33*zc;
            Xp1_3 = fmaf(-DT, h3, X01); Xm1_3 = fmaf(DT, h3, X01);
            // predicted mean (comps 2,3 are exactly z2,z3)
            float s4 = (Xp0a + Xm0a) + (Xp0b + Xm0b);
            zp0 = fmaf(WI, s4, WB*X00);
            float s8 = ((Xp1_0+Xm1_0)+(Xp1_1+Xm1_1)) + ((Xp1_2+Xm1_2)+(Xp1_3+Xm1_3));
            zp1 = fmaf(WI, s8, WM0*X01);
        }

        // ===== dX, comps 0,1 (cols 2,3 comp0 == dc0) =====
        float dc0 = X00 - zp0, dc1 = X01 - zp1;
        float dp0a = Xp0a-zp0, dp0b = Xp0b-zp0, dm0a = Xm0a-zp0, dm0b = Xm0b-zp0;
        float dp1_0 = Xp1_0-zp1, dp1_1 = Xp1_1-zp1, dp1_2 = Xp1_2-zp1, dp1_3 = Xp1_3-zp1;
        float dm1_0 = Xm1_0-zp1, dm1_1 = Xm1_1-zp1, dm1_2 = Xm1_2-zp1, dm1_3 = Xm1_3-zp1;
        float sd = (dp1_2+dm1_2) + (dp1_3+dm1_3);

        if (first) {
            B00=P00; B01=P01; B02=P02; B03=P03; B11=P11;
            B12=P12; B13=P13; B22=P22; B23=P23; B33=P33;
        } else {
            // (0,1) block: general 9-point sums (4 degenerate points have d0=dc0)
            B00 = fmaf(WI, (dp0a*dp0a + dm0a*dm0a) + (dp0b*dp0b + dm0b*dm0b), WA*(dc0*dc0)) + 1.1e-5f;
            B01 = fmaf(WI, ((dp0a*dp1_0 + dm0a*dm1_0) + (dp0b*dp1_1 + dm0b*dm1_1)) + dc0*sd,
                       WC0*(dc0*dc1));
            B11 = fmaf(WI, ((dp1_0*dp1_0 + dm1_0*dm1_0) + (dp1_1*dp1_1 + dm1_1*dm1_1))
                         + ((dp1_2*dp1_2 + dm1_2*dm1_2) + (dp1_3*dp1_3 + dm1_3*dm1_3)),
                       WC0*(dc1*dc1)) + 1.01e-4f;
            // cross block: d{2,3} = +/-G rows -> weighted G-dot of (Xp - Xm)
            float dd0a = Xp0a - Xm0a, dd0b = Xp0b - Xm0b;
            float dd1_0 = Xp1_0-Xm1_0, dd1_1 = Xp1_1-Xm1_1, dd1_2 = Xp1_2-Xm1_2, dd1_3 = Xp1_3-Xm1_3;
            B02 = WI * fmaf(g21, dd0b, g20*dd0a);
            B03 = WI * fmaf(g31, dd0b, g30*dd0a);
            B12 = WI * (fmaf(g21, dd1_1, g20*dd1_0) + g22*dd1_2);
            B13 = WI * (fmaf(g31, dd1_1, g30*dd1_0) + fmaf(g33, dd1_3, g32*dd1_2));
            // (2,3) block: exact via Cholesky row identity: sum wc d2 d2 = P22 + JIT
            B22 = P22 + 3e-6f;   // + JIT (identity) + Q2 + JIT
            B23 = P23;
            B33 = P33 + 3e-6f;
        }

        // ===== measurement transform h on 9 points (4 comp0-degenerate share Y00) =====
        float w0 = X00*X00;  float Y00 = fmaf(AP*X00, w0, X00);
        float w1 = X01*X01;  float Y01 = fmaf(AV*X01, w1, X01);
        float q;
        q = Xp0a*Xp0a;   float Yp0a  = fmaf(AP*Xp0a, q, Xp0a);
        q = Xm0a*Xm0a;   float Ym0a  = fmaf(AP*Xm0a, q, Xm0a);
        q = Xp0b*Xp0b;   float Yp0b  = fmaf(AP*Xp0b, q, Xp0b);
        q = Xm0b*Xm0b;   float Ym0b  = fmaf(AP*Xm0b, q, Xm0b);
        q = Xp1_0*Xp1_0; float Yp1_0 = fmaf(AV*Xp1_0, q, Xp1_0);
        q = Xm1_0*Xm1_0; float Ym1_0 = fmaf(AV*Xm1_0, q, Xm1_0);
        q = Xp1_1*Xp1_1; float Yp1_1 = fmaf(AV*Xp1_1, q, Xp1_1);
        q = Xm1_1*Xm1_1; float Ym1_1 = fmaf(AV*Xm1_1, q, Xm1_1);
        q = Xp1_2*Xp1_2; float Yp1_2 = fmaf(AV*Xp1_2, q, Xp1_2);
        q = Xm1_2*Xm1_2; float Ym1_2 = fmaf(AV*Xm1_2, q, Xm1_2);
        q = Xp1_3*Xp1_3; float Yp1_3 = fmaf(AV*Xp1_3, q, Xp1_3);
        q = Xm1_3*Xm1_3; float Ym1_3 = fmaf(AV*Xm1_3, q, Xm1_3);

        float sy4 = (Yp0a+Ym0a)+(Yp0b+Ym0b);
        float yp0 = fmaf(WI, sy4, WB*Y00);
        float sy8 = ((Yp1_0+Ym1_0)+(Yp1_1+Ym1_1)) + ((Yp1_2+Ym1_2)+(Yp1_3+Ym1_3));
        float yp1 = fmaf(WI, sy8, WM0*Y01);

        float e0c = Y00-yp0, e1c = Y01-yp1;
        float ep0a = Yp0a-yp0, ep0b = Yp0b-yp0, em0a = Ym0a-yp0, em0b = Ym0b-yp0;
        float ep1_0 = Yp1_0-yp1, ep1_1 = Yp1_1-yp1, ep1_2 = Yp1_2-yp1, ep1_3 = Yp1_3-yp1;
        float em1_0 = Ym1_0-yp1, em1_1 = Ym1_1-yp1, em1_2 = Ym1_2-yp1, em1_3 = Ym1_3-yp1;

        // ===== S and P_zy rows 0,1 — group A (center + 4 degenerate, e0=e0c,d0=dc0) =====
        float se  = (ep1_2+em1_2) + (ep1_3+em1_3);
        float E1A = fmaf(WI, se, WC0*e1c);
        float D1A = fmaf(WI, sd, WC0*dc1);
        float s00 = WA*(e0c*e0c);
        float s01 = e0c*E1A;
        float s11 = fmaf(WI, (ep1_2*ep1_2 + em1_2*em1_2) + (ep1_3*ep1_3 + em1_3*em1_3), WC0*(e1c*e1c));
        float pz00 = WA*(e0c*dc0);
        float pz01 = dc0*E1A;
        float pz10 = e0c*D1A;
        float pz11 = fmaf(WI, (dp1_2*ep1_2 + dm1_2*em1_2) + (dp1_3*ep1_3 + dm1_3*em1_3), WC0*(dc1*e1c));
        // group B: 4 full points
        {
            float u0, u1;
            u0 = WI*ep0a; u1 = WI*ep1_0;
            s00 = fmaf(u0, ep0a, s00); s01 = fmaf(u0, ep1_0, s01); s11 = fmaf(u1, ep1_0, s11);
            pz00 = fmaf(u0, dp0a, pz00); pz01 = fmaf(u1, dp0a, pz01);
            pz10 = fmaf(u0, dp1_0, pz10); pz11 = fmaf(u1, dp1_0, pz11);
            u0 = WI*em0a; u1 = WI*em1_0;
            s00 = fmaf(u0, em0a, s00); s01 = fmaf(u0, em1_0, s01); s11 = fmaf(u1, em1_0, s11);
            pz00 = fmaf(u0, dm0a, pz00); pz01 = fmaf(u1, dm0a, pz01);
            pz10 = fmaf(u0, dm1_0, pz10); pz11 = fmaf(u1, dm1_0, pz11);
            u0 = WI*ep0b; u1 = WI*ep1_1;
            s00 = fmaf(u0, ep0b, s00); s01 = fmaf(u0, ep1_1, s01); s11 = fmaf(u1, ep1_1, s11);
            pz00 = fmaf(u0, dp0b, pz00); pz01 = fmaf(u1, dp0b, pz01);
            pz10 = fmaf(u0, dp1_1, pz10); pz11 = fmaf(u1, dp1_1, pz11);
            u0 = WI*em0b; u1 = WI*em1_1;
            s00 = fmaf(u0, em0b, s00); s01 = fmaf(u0, em1_1, s01); s11 = fmaf(u1, em1_1, s11);
            pz00 = fmaf(u0, dm0b, pz00); pz01 = fmaf(u1, dm0b, pz01);
            pz10 = fmaf(u0, dm1_1, pz10); pz11 = fmaf(u1, dm1_1, pz11);
        }
        // P_zy rows 2,3 via G-dot of (Yp - Ym)
        float fy0a = Yp0a - Ym0a, fy0b = Yp0b - Ym0b;
        float fy1_0 = Yp1_0-Ym1_0, fy1_1 = Yp1_1-Ym1_1, fy1_2 = Yp1_2-Ym1_2, fy1_3 = Yp1_3-Ym1_3;
        float pz20 = WI * fmaf(g21, fy0b, g20*fy0a);
        float pz21 = WI * (fmaf(g21, fy1_1, g20*fy1_0) + g22*fy1_2);
        float pz30 = WI * fmaf(g31, fy0b, g30*fy0a);
        float pz31 = WI * (fmaf(g31, fy1_1, g30*fy1_0) + fmaf(g33, fy1_3, g32*fy1_2));

        // ===== gain via direct 2x2 inverse of (S + R + 2*JIT on diag) =====
        float sg00 = s00 + 0.002502f;     // Rd + JIT (S) + JIT (gain chol)
        float sg11 = s11 + 0.002502f;
        float det  = fmaf(sg00, sg11, -(s01*s01));
        float idet = frcp(det);
        float i00 = sg11*idet, i01 = -(s01*idet), i11 = sg00*idet;
        float K00 = fmaf(pz01, i01, pz00*i00), K01 = fmaf(pz01, i11, pz00*i01);
        float K10 = fmaf(pz11, i01, pz10*i00), K11 = fmaf(pz11, i11, pz10*i01);
        float K20 = fmaf(pz21, i01, pz20*i00), K21 = fmaf(pz21, i11, pz20*i01);
        float K30 = fmaf(pz31, i01, pz30*i00), K31 = fmaf(pz31, i11, pz30*i01);

        float nu0 = yv0 - yp0, nu1 = yv1 - yp1;
        z0v = fmaf(K00, nu0, fmaf(K01, nu1, zp0));
        z1v = fmaf(K10, nu0, fmaf(K11, nu1, zp1));
        z2v = fmaf(K20, nu0, fmaf(K21, nu1, z2v));   // zp[2,3] == z[2,3]
        z3v = fmaf(K30, nu0, fmaf(K31, nu1, z3v));

        // ===== P_post = B - K*Pzy^T + JIT*I  (Joseph-simplified, exact to O(JIT*K^2)) =====
        P00 = (B00 + JIT) - fmaf(K01, pz01, K00*pz00);
        P01 =  B01        - fmaf(K01, pz11, K00*pz10);
        P02 =  B02        - fmaf(K01, pz21, K00*pz20);
        P03 =  B03        - fmaf(K01, pz31, K00*pz30);
        P11 = (B11 + JIT) - fmaf(K11, pz11, K10*pz10);
        P12 =  B12        - fmaf(K11, pz21, K10*pz20);
        P13 =  B13        - fmaf(K11, pz31, K10*pz30);
        P22 = (B22 + JIT) - fmaf(K21, pz21, K20*pz20);
        P23 =  B23        - fmaf(K21, pz31, K20*pz30);
        P33 = (B33 + JIT) - fmaf(K31, pz31, K30*pz30);

        // ---- store posterior mean ----
        *reinterpret_cast<float4*>(ob + 4*t) = make_float4(z0v, z1v, z2v, z3v);

        // ---- rotate prefetch pipeline ----
        ycur = ynext; ucur = unext;
        int ty = (t + 2 < TT) ? (t + 2) : (TT - 1);
        int tu = (t + 1 < TT) ? (t + 1) : (TT - 1);
        ynext = *reinterpret_cast<const float2*>(yb + 2*ty);
        unext = ub[tu];
    }
}

extern "C" void kernel_launch(void* const* d_in, const int* in_sizes, int n_in,
                              void* d_out, int out_size, void* d_ws, size_t ws_size,
                              hipStream_t stream) {
    const float* y  = (const float*)d_in[0];   // (B,T,NY)
    const float* u  = (const float*)d_in[1];   // (B,T)
    const float* z0 = (const float*)d_in[2];   // (B,N)
    const float* P0 = (const float*)d_in[3];   // (B,N,N)
    float* out = (float*)d_out;                // (B,T,N)

    ukf_kernel<<<dim3(BB/64), dim3(64), 0, stream>>>(y, u, z0, P0, out);
}

// Round 3
// 173.760 us; speedup vs baseline: 1.7627x; 1.0933x over previous
//
#include <hip/hip_runtime.h>
#include <math.h>

#ifndef __has_builtin
#define __has_builtin(x) 0
#endif

typedef float v2 __attribute__((ext_vector_type(2)));

__device__ __forceinline__ float fsqrt(float x){
#if __has_builtin(__builtin_amdgcn_sqrtf)
    return __builtin_amdgcn_sqrtf(x);
#else
    return sqrtf(x);
#endif
}
__device__ __forceinline__ float frsqrt(float x){
#if __has_builtin(__builtin_amdgcn_rsqf)
    return __builtin_amdgcn_rsqf(x);
#else
    return 1.0f/sqrtf(x);
#endif
}
__device__ __forceinline__ float frcp(float x){
#if __has_builtin(__builtin_amdgcn_rcpf)
    return __builtin_amdgcn_rcpf(x);
#else
    return 1.0f/x;
#endif
}
__device__ __forceinline__ v2 fma2(v2 a, v2 b, v2 c){
#if __has_builtin(__builtin_elementwise_fma)
    return __builtin_elementwise_fma(a,b,c);
#else
    v2 r; r.x = fmaf(a.x,b.x,c.x); r.y = fmaf(a.y,b.y,c.y); return r;
#endif
}
__device__ __forceinline__ v2 bc(float x){ v2 r; r.x = x; r.y = x; return r; }
__device__ __forceinline__ v2 mk(float a, float b){ v2 r; r.x = a; r.y = b; return r; }
__device__ __forceinline__ float fold(v2 a){ return a.x + a.y; }

namespace {
constexpr int TT = 256;
constexpr int BB = 16384;
}

__global__ __launch_bounds__(64)
void ukf_kernel(const float* __restrict__ yg, const float* __restrict__ ug,
                const float* __restrict__ z0g, const float* __restrict__ P0g,
                float* __restrict__ outg)
{
    constexpr float DT  = 0.05f, CD = 0.25f, AP = 0.1f, AV = 0.1f;
    constexpr float JIT = 1e-6f;
    constexpr float CUT = 2.56f;
    constexpr float CJ  = CUT*JIT;
    constexpr float WM0 = -0.5625f, WI = 0.1953125f, WC0 = 1.7975f;
    constexpr float WA  = WC0 + 4.0f*WI;   // 2.57875
    constexpr float WB  = WM0 + 4.0f*WI;   // 0.21875
    constexpr float TDT = 2.0f*DT;         // 0.1

    const int b = blockIdx.x*64 + threadIdx.x;

    // ---- load state (P symmetrized, upper triangle kept) ----
    float z0v = z0g[b*4+0], z1v = z0g[b*4+1], z2v = z0g[b*4+2], z3v = z0g[b*4+3];
    const float* Pb = P0g + (size_t)b*16;
    float P00 = Pb[0];
    float P01 = 0.5f*(Pb[1]+Pb[4]);
    float P02 = 0.5f*(Pb[2]+Pb[8]);
    float P03 = 0.5f*(Pb[3]+Pb[12]);
    float P11 = Pb[5];
    float P12 = 0.5f*(Pb[6]+Pb[9]);
    float P13 = 0.5f*(Pb[7]+Pb[13]);
    float P22 = Pb[10];
    float P23 = 0.5f*(Pb[11]+Pb[14]);
    float P33 = Pb[15];

    const float* yb = yg + (size_t)b*TT*2;
    const float* ub = ug + (size_t)b*TT;
    float*       ob = outg + (size_t)b*TT*4;

    // ---- software prefetch (1 step ahead) ----
    float2 ycur  = *reinterpret_cast<const float2*>(yb);
    float2 ynext = *reinterpret_cast<const float2*>(yb + 2);
    float  ucur  = 0.0f;
    float  unext = ub[0];

    #pragma unroll 1
    for (int t = 0; t < TT; ++t) {
        const bool first = (t == 0);
        const float yv0 = ycur.x, yv1 = ycur.y;

        // ===== G = chol(CUT*(P + JIT*I)) =====
        float a00 = fmaf(CUT, P00, CJ);
        float r0  = frsqrt(a00);
        float g00 = a00*r0;
        float g10 = (CUT*P01)*r0;
        v2 gc0 = mk(CUT*P02, CUT*P03) * bc(r0);                 // {g20,g30}
        float a11 = fmaf(CUT, P11, CJ) - g10*g10;
        float r1  = frsqrt(a11);
        float g11 = a11*r1;
        v2 gc1 = (mk(CUT*P12, CUT*P13) - gc0*bc(g10)) * bc(r1); // {g21,g31}
        float g20 = gc0.x, g30 = gc0.y, g21 = gc1.x, g31 = gc1.y;
        float a22 = (fmaf(CUT, P22, CJ) - g20*g20) - g21*g21;
        float r2  = frsqrt(a22);
        float g22 = a22*r2;
        float g32 = ((CUT*P23 - g30*g20) - g31*g21)*r2;
        float a33 = ((fmaf(CUT, P33, CJ) - g30*g30) - g31*g31) - g32*g32;
        float g33 = fsqrt(a33);
        v2 G0 = mk(g20, g30), G1 = mk(g21, g31), G2 = mk(g22, g32), G3 = mk(0.0f, g33);

        // ===== propagated sigma points, comps 0,1 (packed {plus,minus}) =====
        float X00, X01, zp0, zp1;
        float h2 = 0.0f, h3 = 0.0f;
        v2 X0a, X0b, X1_0, X1_1, X1_2, X1_3;

        if (first) {
            X00 = z0v; X01 = z1v;
            X0a  = mk(z0v+g00, z0v-g00);
            X0b  = bc(z0v);
            X1_0 = mk(z1v+g10, z1v-g10);
            X1_1 = mk(z1v+g11, z1v-g11);
            X1_2 = bc(z1v);
            X1_3 = bc(z1v);
            zp0 = z0v; zp1 = z1v;
        } else {
            float t0c = z0v*z0v;
            float zc  = t0c*z0v;
            X00 = fmaf(DT, z1v, z0v);
            float ac = fmaf(-CD, z1v, ucur);
            ac = fmaf(-z2v, z0v, ac);
            ac = fmaf(-z3v, zc, ac);
            X01 = fmaf(DT, ac, z1v);
            // col0 (all comps perturbed)
            v2 pp = mk(z0v+g00, z0v-g00);
            v2 vv = mk(z1v+g10, z1v-g10);
            v2 kk = mk(z2v+g20, z2v-g20);
            v2 aa = mk(z3v+g30, z3v-g30);
            X0a = fma2(bc(DT), vv, pp);
            v2 c3 = (pp*pp)*pp;
            v2 acc = fma2(bc(-CD), vv, bc(ucur));
            acc = fma2(-kk, pp, acc);
            acc = fma2(-aa, c3, acc);
            X1_0 = fma2(bc(DT), acc, vv);
            // col1 (p unchanged = z0)
            v2 vv1 = mk(z1v+g11, z1v-g11);
            v2 kk1 = mk(z2v+g21, z2v-g21);
            v2 aa1 = mk(z3v+g31, z3v-g31);
            X0b = fma2(bc(DT), vv1, bc(z0v));
            v2 acc1 = fma2(bc(-CD), vv1, bc(ucur));
            acc1 = fma2(-kk1, bc(z0v), acc1);
            acc1 = fma2(-aa1, bc(zc), acc1);
            X1_1 = fma2(bc(DT), acc1, vv1);
            // cols 2,3: v-only shift
            h2 = fmaf(g32, zc, g22*z0v);
            h3 = g33*zc;
            X1_2 = mk(fmaf(-DT, h2, X01), fmaf(DT, h2, X01));
            X1_3 = mk(fmaf(-DT, h3, X01), fmaf(DT, h3, X01));
            // predicted mean (comps 2,3 == z2,z3)
            zp0 = fmaf(WI, fold(X0a + X0b), WB*X00);
            zp1 = fmaf(WI, fold((X1_0 + X1_1) + (X1_2 + X1_3)), WM0*X01);
        }

        // ===== dX (packed) =====
        float dc0 = X00 - zp0, dc1 = X01 - zp1;
        v2 d0a  = X0a  - bc(zp0);
        v2 d0b  = X0b  - bc(zp0);
        v2 d1_0 = X1_0 - bc(zp1);
        v2 d1_1 = X1_1 - bc(zp1);
        v2 d1_2 = X1_2 - bc(zp1);
        v2 d1_3 = X1_3 - bc(zp1);
        float sd = fold(d1_2 + d1_3);

        // ===== P_pred =====
        float B00, B01, B11, B22, B23, B33;
        v2 B02_03, B12_13;
        if (first) {
            B00 = P00; B01 = P01; B11 = P11; B22 = P22; B23 = P23; B33 = P33;
            B02_03 = mk(P02, P03); B12_13 = mk(P12, P13);
        } else {
            v2 t00 = d0a*d0a + d0b*d0b;
            B00 = fmaf(WI, fold(t00), WA*(dc0*dc0)) + 1.1e-5f;
            v2 t01 = d0a*d1_0 + d0b*d1_1;
            B01 = fmaf(WI, fold(t01) + dc0*sd, WC0*(dc0*dc1));
            v2 t11 = (d1_0*d1_0 + d1_1*d1_1) + (d1_2*d1_2 + d1_3*d1_3);
            B11 = fmaf(WI, fold(t11), WC0*(dc1*dc1)) + 1.01e-4f;
            float dd0a = X0a.x - X0a.y, dd0b = X0b.x - X0b.y;
            float dd1_0 = X1_0.x - X1_0.y, dd1_1 = X1_1.x - X1_1.y;
            B02_03 = (G0*bc(dd0a) + G1*bc(dd0b)) * bc(WI);
            v2 bt = fma2(G1, bc(dd1_1), G0*bc(dd1_0));
            bt = fma2(G2, bc(-TDT*h2), bt);
            bt = fma2(G3, bc(-TDT*h3), bt);
            B12_13 = bt * bc(WI);
            B22 = P22 + 3e-6f;
            B23 = P23;
            B33 = P33 + 3e-6f;
        }

        // ===== measurement transform (packed) =====
        float w0 = X00*X00;  float Y00 = fmaf(AP*X00, w0, X00);
        float w1 = X01*X01;  float Y01 = fmaf(AV*X01, w1, X01);
        v2 Y0a  = fma2(bc(AP)*X0a,  X0a*X0a,   X0a);
        v2 Y0b  = fma2(bc(AP)*X0b,  X0b*X0b,   X0b);
        v2 Y1_0 = fma2(bc(AV)*X1_0, X1_0*X1_0, X1_0);
        v2 Y1_1 = fma2(bc(AV)*X1_1, X1_1*X1_1, X1_1);
        v2 Y1_2 = fma2(bc(AV)*X1_2, X1_2*X1_2, X1_2);
        v2 Y1_3 = fma2(bc(AV)*X1_3, X1_3*X1_3, X1_3);

        float yp0 = fmaf(WI, fold(Y0a + Y0b), WB*Y00);
        float yp1 = fmaf(WI, fold((Y1_0 + Y1_1) + (Y1_2 + Y1_3)), WM0*Y01);

        float e0c = Y00 - yp0, e1c = Y01 - yp1;
        v2 e0a  = Y0a  - bc(yp0);
        v2 e0b  = Y0b  - bc(yp0);
        v2 e1_0 = Y1_0 - bc(yp1);
        v2 e1_1 = Y1_1 - bc(yp1);
        v2 e1_2 = Y1_2 - bc(yp1);
        v2 e1_3 = Y1_3 - bc(yp1);

        // ===== S and P_zy rows 0,1 — group A (center + degenerate) =====
        float se  = fold(e1_2 + e1_3);
        float E1A = fmaf(WI, se, WC0*e1c);
        float D1A = fmaf(WI, sd, WC0*dc1);
        float s00 = WA*(e0c*e0c);
        float s01 = e0c*E1A;
        float s11 = fmaf(WI, fold(e1_2*e1_2 + e1_3*e1_3), WC0*(e1c*e1c));
        float pz00 = WA*(e0c*dc0);
        float pz01 = dc0*E1A;
        float pz10 = e0c*D1A;
        float pz11 = fmaf(WI, fold(d1_2*e1_2 + d1_3*e1_3), WC0*(dc1*e1c));
        // group B: 4 full points (packed)
        v2 bs00 = e0a*e0a   + e0b*e0b;
        v2 bs01 = e0a*e1_0  + e0b*e1_1;
        v2 bs11 = e1_0*e1_0 + e1_1*e1_1;
        v2 bp00 = e0a*d0a   + e0b*d0b;
        v2 bp01 = e1_0*d0a  + e1_1*d0b;
        v2 bp10 = e0a*d1_0  + e0b*d1_1;
        v2 bp11 = e1_0*d1_0 + e1_1*d1_1;
        s00  = fmaf(WI, fold(bs00), s00);
        s01  = fmaf(WI, fold(bs01), s01);
        s11  = fmaf(WI, fold(bs11), s11);
        pz00 = fmaf(WI, fold(bp00), pz00);
        pz01 = fmaf(WI, fold(bp01), pz01);
        pz10 = fmaf(WI, fold(bp10), pz10);
        pz11 = fmaf(WI, fold(bp11), pz11);

        // P_zy rows 2,3 via G-dot of (Yplus - Yminus), packed over row index
        float fy0a  = Y0a.x  - Y0a.y,  fy0b  = Y0b.x  - Y0b.y;
        float fy1_0 = Y1_0.x - Y1_0.y, fy1_1 = Y1_1.x - Y1_1.y;
        float fy1_2 = Y1_2.x - Y1_2.y, fy1_3 = Y1_3.x - Y1_3.y;
        v2 pzc0 = (G0*bc(fy0a) + G1*bc(fy0b)) * bc(WI);          // {pz20,pz30}
        v2 pt = fma2(G1, bc(fy1_1), G0*bc(fy1_0));
        pt = fma2(G2, bc(fy1_2), pt);
        pt = fma2(G3, bc(fy1_3), pt);
        v2 pzc1 = pt * bc(WI);                                    // {pz21,pz31}

        // ===== gain via direct 2x2 inverse =====
        float sg00 = s00 + 0.002502f;     // Rd + 2*JIT
        float sg11 = s11 + 0.002502f;
        float det  = fmaf(sg00, sg11, -(s01*s01));
        float idet = frcp(det);
        float i00 = sg11*idet, i01 = -(s01*idet), i11 = sg00*idet;
        v2 Si0 = mk(i00, i01), Si1 = mk(i01, i11);
        v2 K0 = fma2(bc(pz01),   Si1, bc(pz00)  *Si0);   // {K00,K01}
        v2 K1 = fma2(bc(pz11),   Si1, bc(pz10)  *Si0);
        v2 K2 = fma2(bc(pzc1.x), Si1, bc(pzc0.x)*Si0);
        v2 K3 = fma2(bc(pzc1.y), Si1, bc(pzc0.y)*Si0);

        float nu0 = yv0 - yp0, nu1 = yv1 - yp1;
        z0v = fmaf(K0.x, nu0, fmaf(K0.y, nu1, zp0));
        z1v = fmaf(K1.x, nu0, fmaf(K1.y, nu1, zp1));
        z2v = fmaf(K2.x, nu0, fmaf(K2.y, nu1, z2v));
        z3v = fmaf(K3.x, nu0, fmaf(K3.y, nu1, z3v));

        // ===== P_post = B - K*Pzy^T + JIT*I (packed over entry pairs) =====
        v2 pc0 = mk(pz00, pz10), pc1 = mk(pz01, pz11);
        v2 u01 = fma2(bc(K0.y), pc1, bc(K0.x)*pc0);      // {K0.row0, K0.row1}
        v2 P0001 = mk(B00 + JIT, B01) - u01;
        P00 = P0001.x; P01 = P0001.y;
        P11 = (B11 + JIT) - fmaf(K1.y, pz11, K1.x*pz10);
        v2 u2 = fma2(bc(K0.y), pzc1, bc(K0.x)*pzc0);     // {K0.row2, K0.row3}
        v2 P0203 = B02_03 - u2;
        P02 = P0203.x; P03 = P0203.y;
        v2 u3 = fma2(bc(K1.y), pzc1, bc(K1.x)*pzc0);
        v2 P1213 = B12_13 - u3;
        P12 = P1213.x; P13 = P1213.y;
        v2 u4 = fma2(bc(K2.y), pzc1, bc(K2.x)*pzc0);     // {K2.row2, K2.row3}
        v2 P2223 = mk(B22 + JIT, B23) - u4;
        P22 = P2223.x; P23 = P2223.y;
        P33 = (B33 + JIT) - fmaf(K3.y, pzc1.y, K3.x*pzc0.y);

        // ---- store posterior mean ----
        *reinterpret_cast<float4*>(ob + 4*t) = make_float4(z0v, z1v, z2v, z3v);

        // ---- rotate prefetch pipeline ----
        ycur = ynext; ucur = unext;
        int ty = (t + 2 < TT) ? (t + 2) : (TT - 1);
        int tu = (t + 1 < TT) ? (t + 1) : (TT - 1);
        ynext = *reinterpret_cast<const float2*>(yb + 2*ty);
        unext = ub[tu];
    }
}

extern "C" void kernel_launch(void* const* d_in, const int* in_sizes, int n_in,
                              void* d_out, int out_size, void* d_ws, size_t ws_size,
                              hipStream_t stream) {
    const float* y  = (const float*)d_in[0];   // (B,T,NY)
    const float* u  = (const float*)d_in[1];   // (B,T)
    const float* z0 = (const float*)d_in[2];   // (B,N)
    const float* P0 = (const float*)d_in[3];   // (B,N,N)
    float* out = (float*)d_out;                // (B,T,N)

    ukf_kernel<<<dim3(BB/64), dim3(64), 0, stream>>>(y, u, z0, P0, out);
}

// Round 4
// 153.534 us; speedup vs baseline: 1.9949x; 1.1317x over previous
//
#include <hip/hip_runtime.h>
#include <math.h>

#ifndef __has_builtin
#define __has_builtin(x) 0
#endif

__device__ __forceinline__ float fsqrt(float x){
#if __has_builtin(__builtin_amdgcn_sqrtf)
    return __builtin_amdgcn_sqrtf(x);
#else
    return sqrtf(x);
#endif
}
__device__ __forceinline__ float frsqrt(float x){
#if __has_builtin(__builtin_amdgcn_rsqf)
    return __builtin_amdgcn_rsqf(x);
#else
    return 1.0f/sqrtf(x);
#endif
}
__device__ __forceinline__ float frcp(float x){
#if __has_builtin(__builtin_amdgcn_rcpf)
    return __builtin_amdgcn_rcpf(x);
#else
    return 1.0f/x;
#endif
}

namespace {
constexpr int TT = 256;
constexpr int BB = 16384;
}

__global__ __launch_bounds__(64)
void ukf_kernel(const float* __restrict__ yg, const float* __restrict__ ug,
                const float* __restrict__ z0g, const float* __restrict__ P0g,
                float* __restrict__ outg)
{
    constexpr float DT  = 0.05f, CD = 0.25f, AP = 0.1f, AV = 0.1f;
    constexpr float JIT = 1e-6f;
    constexpr float CUT = 2.56f, CJ = CUT*JIT;
    constexpr float CVV = 1.0f - DT*CD;          // 0.9875
    constexpr float WM0 = -0.5625f, WC0 = 1.7975f;
    constexpr float W2  = 0.390625f;             // 2*WI
    constexpr float WB  = 0.21875f;              // WM0 + 4WI
    constexpr float WA  = 2.57875f;              // WC0 + 4WI
    // B11 q-coefficient: (WC0+6WI)*(2WI)^2 + 2WI*(1-2WI)^2 (exact)
    constexpr float CQ2 = 0.59814453125f;

    const int b = blockIdx.x*64 + threadIdx.x;

    float z0v = z0g[b*4+0], z1v = z0g[b*4+1], z2v = z0g[b*4+2], z3v = z0g[b*4+3];
    const float* Pb = P0g + (size_t)b*16;
    float P00 = Pb[0];
    float P01 = 0.5f*(Pb[1]+Pb[4]);
    float P02 = 0.5f*(Pb[2]+Pb[8]);
    float P03 = 0.5f*(Pb[3]+Pb[12]);
    float P11 = Pb[5];
    float P12 = 0.5f*(Pb[6]+Pb[9]);
    float P13 = 0.5f*(Pb[7]+Pb[13]);
    float P22 = Pb[10];
    float P23 = 0.5f*(Pb[11]+Pb[14]);
    float P33 = Pb[15];

    const float* yb = yg + (size_t)b*TT*2;
    const float* ub = ug + (size_t)b*TT;
    float*       ob = outg + (size_t)b*TT*4;

    // Cholesky factors live across the update
    float g00,g10,g20,g30,g11,g21,g31,g22,g32,g33;

    // chol of CUT*(P + JIT I)  (sqrt(c) folded)
    auto chol = [&](){
        float a00 = fmaf(CUT,P00,CJ);
        float r0  = frsqrt(a00);
        g00 = a00*r0;
        g10 = (CUT*P01)*r0;
        g20 = (CUT*P02)*r0;
        g30 = (CUT*P03)*r0;
        float a11 = fmaf(CUT,P11,CJ) - g10*g10;
        float r1  = frsqrt(a11);
        g11 = a11*r1;
        g21 = (CUT*P12 - g20*g10)*r1;
        g31 = (CUT*P13 - g30*g10)*r1;
        float a22 = (fmaf(CUT,P22,CJ) - g20*g20) - g21*g21;
        float r2  = frsqrt(a22);
        g22 = a22*r2;
        g32 = ((CUT*P23 - g30*g20) - g31*g21)*r2;
        float a33 = ((fmaf(CUT,P33,CJ) - g30*g30) - g31*g31) - g32*g32;
        g33 = fsqrt(a33);
    };

    // measurement update via odd/even closed forms.
    // Xp/Xm: comp1 col0 sigma values; D10/q precomputed (t0: g10, 0).
    auto update = [&](float X00, float X01, float Xp, float Xm,
                      float D10, float q,
                      float D00, float D01, float D11, float D12, float D13,
                      float B00,float B01,float B02,float B03,float B11,
                      float B12,float B13,float B22,float B23,float B33,
                      float yv0, float yv1)
    {
        float eps_c = -W2*q;
        float eps_a = q + eps_c;              // (1-2WI) q
        float zp1   = fmaf(W2, q, X01);       // zp0 = X00 exactly

        // h at center
        float w0 = X00*X00, w1 = X01*X01;
        float apx = AP*X00, avx = AV*X01;
        float Y00 = fmaf(apx, w0, X00);
        float Y01 = fmaf(avx, w1, X01);
        float cp  = fmaf(0.3f, w0, 1.0f);
        float cv  = fmaf(0.3f, w1, 1.0f);
        float e3p = 3.0f*apx, e3v = 3.0f*avx;

        // comp0 cols 0,1 closed form
        float D00sq = D00*D00, D01sq = D01*D01;
        float Ev00 = fmaf(e3p, D00sq, Y00);
        float Ev01 = fmaf(e3p, D01sq, Y00);
        float Od00 = D00*fmaf(AP, D00sq, cp);
        float Od01 = D01*fmaf(AP, D01sq, cp);

        // comp1 col0: explicit h on the two propagated points
        float sp = Xp*Xp, sm = Xm*Xm;
        float Yp = fmaf(AV*Xp, sp, Xp);
        float Ym = fmaf(AV*Xm, sm, Xm);
        float Evy0 = 0.5f*(Yp+Ym), Q0 = 0.5f*(Yp-Ym);

        // comp1 cols 1..3 closed form
        float D11sq = D11*D11, D12sq = D12*D12, D13sq = D13*D13;
        float Ev11 = fmaf(e3v, D11sq, Y01);
        float Ev12 = fmaf(e3v, D12sq, Y01);
        float Ev13 = fmaf(e3v, D13sq, Y01);
        float Q1 = D11*fmaf(AV, D11sq, cv);
        float Q2 = D12*fmaf(AV, D12sq, cv);
        float Q3 = D13*fmaf(AV, D13sq, cv);

        float yp0 = fmaf(W2, Ev00+Ev01, WB*Y00);
        float yp1 = fmaf(W2, (Evy0+Ev11)+(Ev12+Ev13), WM0*Y01);

        float ec0 = Y00 - yp0, ec1 = Y01 - yp1;
        float xi0 = Ev00 - yp0, xi1 = Ev01 - yp0;
        float et0 = Evy0 - yp1, et1 = Ev11 - yp1, et2 = Ev12 - yp1, et3 = Ev13 - yp1;
        float et23 = et2 + et3;

        // S (2x2)
        float Ts00 = fmaf(Od00,Od00, xi0*xi0);
        Ts00 = fmaf(xi1,xi1,Ts00); Ts00 = fmaf(Od01,Od01,Ts00);
        float s00 = fmaf(W2, Ts00, WA*(ec0*ec0));
        float Ts01 = fmaf(Od00, Q0, xi0*et0);
        Ts01 = fmaf(xi1, et1, Ts01); Ts01 = fmaf(Od01, Q1, Ts01);
        Ts01 = fmaf(ec0, et23, Ts01);
        float s01 = fmaf(W2, Ts01, WC0*(ec0*ec1));
        float Ts11 = fmaf(Q0,Q0, et0*et0);
        Ts11 = fmaf(et1,et1,Ts11); Ts11 = fmaf(Q1,Q1,Ts11);
        Ts11 = fmaf(et2,et2,Ts11); Ts11 = fmaf(Q2,Q2,Ts11);
        Ts11 = fmaf(et3,et3,Ts11); Ts11 = fmaf(Q3,Q3,Ts11);
        float s11 = fmaf(W2, Ts11, WC0*(ec1*ec1));

        // P_zy
        float pz00 = W2*fmaf(D01, Od01, D00*Od00);
        float pz01 = W2*fmaf(D01, Q1, D00*Q0);
        float Tp10 = fmaf(D10, Od00, eps_a*xi0);
        Tp10 = fmaf(eps_c, xi1, Tp10); Tp10 = fmaf(D11, Od01, Tp10);
        float pz10 = fmaf(W2, Tp10, WA*(eps_c*ec0));
        float et123 = et1 + et23;
        float Tp11 = fmaf(D10, Q0, eps_a*et0);
        Tp11 = fmaf(eps_c, et123, Tp11);
        Tp11 = fmaf(D11, Q1, Tp11);
        Tp11 = fmaf(D12, Q2, Tp11);
        Tp11 = fmaf(D13, Q3, Tp11);
        float pz11 = fmaf(W2, Tp11, WC0*(eps_c*ec1));
        float pz20 = W2*fmaf(g21, Od01, g20*Od00);
        float pz30 = W2*fmaf(g31, Od01, g30*Od00);
        float Tp21 = fmaf(g21, Q1, g20*Q0); Tp21 = fmaf(g22, Q2, Tp21);
        float pz21 = W2*Tp21;
        float Tp31 = fmaf(g31, Q1, g30*Q0); Tp31 = fmaf(g32, Q2, Tp31);
        Tp31 = fmaf(g33, Q3, Tp31);
        float pz31 = W2*Tp31;

        // gain via direct 2x2 inverse (S + R + 2 JIT on diag)
        float sg00 = s00 + 0.002502f, sg11 = s11 + 0.002502f;
        float det  = fmaf(sg00, sg11, -(s01*s01));
        float idet = frcp(det);
        float i00 = sg11*idet, i01 = -(s01*idet), i11 = sg00*idet;
        float K00 = fmaf(pz01,i01, pz00*i00), K01 = fmaf(pz01,i11, pz00*i01);
        float K10 = fmaf(pz11,i01, pz10*i00), K11 = fmaf(pz11,i11, pz10*i01);
        float K20 = fmaf(pz21,i01, pz20*i00), K21 = fmaf(pz21,i11, pz20*i01);
        float K30 = fmaf(pz31,i01, pz30*i00), K31 = fmaf(pz31,i11, pz30*i01);

        float nu0 = yv0 - yp0, nu1 = yv1 - yp1;
        z0v = fmaf(K00,nu0, fmaf(K01,nu1, X00));
        z1v = fmaf(K10,nu0, fmaf(K11,nu1, zp1));
        z2v = fmaf(K20,nu0, fmaf(K21,nu1, z2v));
        z3v = fmaf(K30,nu0, fmaf(K31,nu1, z3v));

        // P_post = B - K Pzy^T + JIT I
        P00 = (B00+JIT) - fmaf(K01,pz01, K00*pz00);
        P01 =  B01      - fmaf(K01,pz11, K00*pz10);
        P02 =  B02      - fmaf(K01,pz21, K00*pz20);
        P03 =  B03      - fmaf(K01,pz31, K00*pz30);
        P11 = (B11+JIT) - fmaf(K11,pz11, K10*pz10);
        P12 =  B12      - fmaf(K11,pz21, K10*pz20);
        P13 =  B13      - fmaf(K11,pz31, K10*pz30);
        P22 = (B22+JIT) - fmaf(K21,pz21, K20*pz20);
        P23 =  B23      - fmaf(K21,pz31, K20*pz30);
        P33 = (B33+JIT) - fmaf(K31,pz31, K30*pz30);
    };

    // ---- prefetch ----
    float2 ycur  = *reinterpret_cast<const float2*>(yb);
    float2 ynext = *reinterpret_cast<const float2*>(yb + 2);
    float  unext = ub[0];

    // ================= t = 0 (no dynamics; P_pred = P0) =================
    chol();
    update(z0v, z1v, z1v+g10, z1v-g10,
           g10, 0.0f,
           g00, 0.0f, g11, 0.0f, 0.0f,
           P00,P01,P02,P03,P11,P12,P13,P22,P23,P33,
           ycur.x, ycur.y);
    *reinterpret_cast<float4*>(ob) = make_float4(z0v, z1v, z2v, z3v);

    // ================= main loop t = 1..255 =================
    #pragma unroll 1
    for (int t = 1; t < TT; ++t) {
        float yv0 = ynext.x, yv1 = ynext.y;
        float uu  = unext;
        // prefetch t+1
        int tn = (t+1 < TT) ? (t+1) : (TT-1);
        ynext = *reinterpret_cast<const float2*>(yb + 2*tn);
        unext = ub[t];

        chol();

        // center dynamics
        float w  = z0v*z0v;
        float zc = w*z0v;                       // p^3 at center
        float X00 = fmaf(DT, z1v, z0v);
        float ac = fmaf(-CD, z1v, uu);
        ac = fmaf(-z2v, z0v, ac);
        ac = fmaf(-z3v, zc, ac);
        float X01 = fmaf(DT, ac, z1v);

        // col0 explicit propagation (comp1 only is nonlinear)
        float pp = z0v+g00, pm = z0v-g00;
        float vp = z1v+g10, vm = z1v-g10;
        float kp = z2v+g20, km = z2v-g20;
        float aap = z3v+g30, aam = z3v-g30;
        float cp3 = (pp*pp)*pp, cm3 = (pm*pm)*pm;
        float accp = fmaf(-CD, vp, uu); accp = fmaf(-kp,pp,accp); accp = fmaf(-aap,cp3,accp);
        float Xp = fmaf(DT, accp, vp);
        float accm = fmaf(-CD, vm, uu); accm = fmaf(-km,pm,accm); accm = fmaf(-aam,cm3,accm);
        float Xm = fmaf(DT, accm, vm);
        float D10 = 0.5f*(Xp - Xm);
        float q   = fmaf(0.5f, Xp + Xm, -X01);

        // odd propagation closed forms
        float D00 = fmaf(DT, g10, g00);
        float D01 = DT*g11;
        float ha  = fmaf(g31, zc, g21*z0v);
        float D11 = fmaf(CVV, g11, -(DT*ha));
        float hb  = fmaf(g32, zc, g22*z0v);
        float D12 = -(DT*hb);
        float D13 = -(DT*(g33*zc));

        // P_pred
        float B00 = fmaf(W2, fmaf(D01,D01, D00*D00), 1.1e-5f);
        float B01 = W2 * fmaf(D01, D11, D00*D10);
        float B02 = W2 * fmaf(D01, g21, D00*g20);
        float B03 = W2 * fmaf(D01, g31, D00*g30);
        float TB11 = fmaf(D11,D11, D10*D10);
        TB11 = fmaf(D12,D12,TB11); TB11 = fmaf(D13,D13,TB11);
        float B11 = fmaf(W2, TB11, fmaf(CQ2, q*q, 1.01e-4f));
        float TB12 = fmaf(D11,g21, D10*g20); TB12 = fmaf(D12,g22,TB12);
        float B12 = W2*TB12;
        float TB13 = fmaf(D11,g31, D10*g30); TB13 = fmaf(D12,g32,TB13);
        TB13 = fmaf(D13,g33,TB13);
        float B13 = W2*TB13;
        float B22 = P22 + 3e-6f;
        float B23 = P23;
        float B33 = P33 + 3e-6f;

        update(X00, X01, Xp, Xm, D10, q, D00, D01, D11, D12, D13,
               B00,B01,B02,B03,B11,B12,B13,B22,B23,B33, yv0, yv1);

        *reinterpret_cast<float4*>(ob + 4*t) = make_float4(z0v, z1v, z2v, z3v);
    }
}

extern "C" void kernel_launch(void* const* d_in, const int* in_sizes, int n_in,
                              void* d_out, int out_size, void* d_ws, size_t ws_size,
                              hipStream_t stream) {
    const float* y  = (const float*)d_in[0];   // (B,T,NY)
    const float* u  = (const float*)d_in[1];   // (B,T)
    const float* z0 = (const float*)d_in[2];   // (B,N)
    const float* P0 = (const float*)d_in[3];   // (B,N,N)
    float* out = (float*)d_out;                // (B,T,N)

    ukf_kernel<<<dim3(BB/64), dim3(64), 0, stream>>>(y, u, z0, P0, out);
}

// Round 5
// 129.583 us; speedup vs baseline: 2.3636x; 1.1848x over previous
//
#include <hip/hip_runtime.h>
#include <math.h>

#ifndef __has_builtin
#define __has_builtin(x) 0
#endif

__device__ __forceinline__ float fsqrt(float x){
#if __has_builtin(__builtin_amdgcn_sqrtf)
    return __builtin_amdgcn_sqrtf(x);
#else
    return sqrtf(x);
#endif
}
__device__ __forceinline__ float frsqrt(float x){
#if __has_builtin(__builtin_amdgcn_rsqf)
    return __builtin_amdgcn_rsqf(x);
#else
    return 1.0f/sqrtf(x);
#endif
}
__device__ __forceinline__ float frcp(float x){
#if __has_builtin(__builtin_amdgcn_rcpf)
    return __builtin_amdgcn_rcpf(x);
#else
    return 1.0f/x;
#endif
}

namespace {
constexpr int TT = 256;
constexpr int BB = 16384;
}

__global__ __launch_bounds__(64)
void ukf_kernel(const float* __restrict__ yg, const float* __restrict__ ug,
                const float* __restrict__ z0g, const float* __restrict__ P0g,
                float* __restrict__ outg)
{
    constexpr float DT  = 0.05f, CD = 0.25f, AP = 0.1f, AV = 0.1f;
    constexpr float CJ  = 2.56e-6f;              // CUT*JIT
    constexpr float CVV = 1.0f - DT*CD;          // 0.9875
    constexpr float WM0 = -0.5625f, WC0 = 1.7975f;
    constexpr float W2  = 0.390625f;             // 2*WI ; note CUT*W2 == 1.0 exactly
    constexpr float WA  = 2.57875f;              // WC0 + 4WI
    constexpr float WAC = 6.6016f;               // CUT*WA
    constexpr float WCC = 4.6016f;               // CUT*WC0
    constexpr float W2E = 0.1171875f;            // W2*0.3
    constexpr float RSG = 0.00640512f;           // CUT*(Rd + 2*JIT)
    constexpr float CQ2C = 1.53125f;             // CUT*CQ2
    constexpr float CB00 = 3.072e-5f;            // CUT*(Q00 + 2JIT)
    constexpr float CB11 = 2.6112e-4f;           // CUT*(Q11 + 2JIT)
    constexpr float CB22 = 1.024e-5f;            // CUT*(idJIT + Q22 + 2JIT)
    constexpr float HCUT = 1.28f;                // 0.5*CUT (symmetrize+scale)
    constexpr float CUTc = 2.56f;

    const int b = blockIdx.x*64 + threadIdx.x;

    float z0v = z0g[b*4+0], z1v = z0g[b*4+1], z2v = z0g[b*4+2], z3v = z0g[b*4+3];
    const float* Pb = P0g + (size_t)b*16;
    // Pc = CUT * sym(P0)
    float P00 = CUTc*Pb[0];
    float P01 = HCUT*(Pb[1]+Pb[4]);
    float P02 = HCUT*(Pb[2]+Pb[8]);
    float P03 = HCUT*(Pb[3]+Pb[12]);
    float P11 = CUTc*Pb[5];
    float P12 = HCUT*(Pb[6]+Pb[9]);
    float P13 = HCUT*(Pb[7]+Pb[13]);
    float P22 = CUTc*Pb[10];
    float P23 = HCUT*(Pb[11]+Pb[14]);
    float P33 = CUTc*Pb[15];

    const float* yb = yg + (size_t)b*TT*2;
    const float* ub = ug + (size_t)b*TT;
    float*       ob = outg + (size_t)b*TT*4;

    float g00,g10,g20,g30,g11,g21,g31,g22,g32,g33;

    // G = chol(Pc + CJ*I)   (== chol(CUT*(P+JIT I)), sqrt(c) folded)
    auto chol = [&](){
        float a00 = P00 + CJ;
        float r0  = frsqrt(a00);
        g00 = a00*r0;
        g10 = P01*r0;
        g20 = P02*r0;
        g30 = P03*r0;
        float a11 = fmaf(-g10,g10, P11 + CJ);
        float r1  = frsqrt(a11);
        g11 = a11*r1;
        g21 = fmaf(-g20,g10, P12)*r1;
        g31 = fmaf(-g30,g10, P13)*r1;
        float a22 = fmaf(-g21,g21, fmaf(-g20,g20, P22 + CJ));
        float r2  = frsqrt(a22);
        g22 = a22*r2;
        g32 = fmaf(-g31,g21, fmaf(-g30,g20, P23))*r2;
        float a33 = fmaf(-g32,g32, fmaf(-g31,g31, fmaf(-g30,g30, P33 + CJ)));
        g33 = fsqrt(a33);
    };

    // Measurement update. All B/pz/S quantities CUT-scaled (Pc convention);
    // K comes out exact (CUT cancels in pz'*S'^-1).
    auto update = [&](float X00, float X01, float Xp, float Xm,
                      float D10, float q,
                      float D00, float D01, float D11, float D12, float D13,
                      float B00p,float B01p,float B02p,float B03p,float B11p,
                      float B12p,float B13p,float B22p,float B23p,float B33p,
                      float yv0, float yv1)
    {
        float eps_c = -W2*q;
        float eps_a = q + eps_c;              // (1-2WI) q
        float zp1   = fmaf(W2, q, X01);       // zp0 == X00 exactly

        // h at center + derivative-like consts
        float w0 = X00*X00, w1 = X01*X01;
        float apx = AP*X00, avx = AV*X01;
        float Y00 = fmaf(apx, w0, X00);
        float Y01 = fmaf(avx, w1, X01);
        float cp  = fmaf(0.3f, w0, 1.0f);
        float cv  = fmaf(0.3f, w1, 1.0f);
        float e3p = 0.3f*X00, e3v = 0.3f*X01;
        float w2e3p = W2E*X00;

        // comp0 cols 0,1 (closed form)
        float D00sq = D00*D00, D01sq = D01*D01;
        float SD0 = D00sq + D01sq;
        float yp0 = fmaf(w2e3p, SD0, Y00);
        float ec0 = Y00 - yp0;
        float xi0 = fmaf(e3p, D00sq, ec0);
        float xi1 = fmaf(e3p, D01sq, ec0);
        float Od00 = D00*fmaf(AP, D00sq, cp);
        float Od01 = D01*fmaf(AP, D01sq, cp);

        // comp1 col0: explicit h on the two propagated points
        float sp = Xp*Xp, sm = Xm*Xm;
        float Yp = fmaf(AV*Xp, sp, Xp);
        float Ym = fmaf(AV*Xm, sm, Xm);
        float qy = fmaf(0.5f, Yp + Ym, -Y01);      // even excess
        float Q0 = 0.5f*(Yp - Ym);

        // comp1 cols 1..3 (closed form)
        float D11sq = D11*D11, D12sq = D12*D12, D13sq = D13*D13;
        float SD1 = (D11sq + D12sq) + D13sq;
        float inner = fmaf(e3v, SD1, qy);
        float yp1 = fmaf(W2, inner, Y01);
        float ec1 = Y01 - yp1;
        float et0 = qy + ec1;                      // Evy0 - yp1
        float et1 = fmaf(e3v, D11sq, ec1);
        float et2 = fmaf(e3v, D12sq, ec1);
        float et3 = fmaf(e3v, D13sq, ec1);
        float Q1 = D11*fmaf(AV, D11sq, cv);
        float Q2 = D12*fmaf(AV, D12sq, cv);
        float Q3 = D13*fmaf(AV, D13sq, cv);
        float et23 = et2 + et3;

        // ===== S' = CUT*S (2x2) =====
        float Ts00 = fmaf(Od00,Od00, xi0*xi0);
        Ts00 = fmaf(xi1,xi1,Ts00); Ts00 = fmaf(Od01,Od01,Ts00);
        float s00 = fmaf(WAC, ec0*ec0, Ts00);
        float Ts01 = fmaf(Od00, Q0, xi0*et0);
        Ts01 = fmaf(xi1, et1, Ts01); Ts01 = fmaf(Od01, Q1, Ts01);
        Ts01 = fmaf(ec0, et23, Ts01);
        float s01 = fmaf(WCC, ec0*ec1, Ts01);
        float Ts11 = fmaf(Q0,Q0, et0*et0);
        Ts11 = fmaf(et1,et1,Ts11); Ts11 = fmaf(Q1,Q1,Ts11);
        Ts11 = fmaf(et2,et2,Ts11); Ts11 = fmaf(Q2,Q2,Ts11);
        Ts11 = fmaf(et3,et3,Ts11); Ts11 = fmaf(Q3,Q3,Ts11);
        float s11 = fmaf(WCC, ec1*ec1, Ts11);

        // ===== pz' = CUT*P_zy  (CUT*W2 == 1 absorbs all W2 factors) =====
        float pz00 = fmaf(D01, Od01, D00*Od00);
        float pz01 = fmaf(D01, Q1, D00*Q0);
        float Tp10 = fmaf(D10, Od00, eps_a*xi0);
        Tp10 = fmaf(eps_c, xi1, Tp10); Tp10 = fmaf(D11, Od01, Tp10);
        float pz10 = fmaf(-WA, q*ec0, Tp10);       // CUT*eps_c == -q
        float et123 = et1 + et23;
        float Tp11 = fmaf(D10, Q0, eps_a*et0);
        Tp11 = fmaf(eps_c, et123, Tp11);
        Tp11 = fmaf(D11, Q1, Tp11);
        Tp11 = fmaf(D12, Q2, Tp11);
        Tp11 = fmaf(D13, Q3, Tp11);
        float pz11 = fmaf(-WC0, q*ec1, Tp11);
        float pz20 = fmaf(g21, Od01, g20*Od00);
        float pz30 = fmaf(g31, Od01, g30*Od00);
        float pz21 = fmaf(g21, Q1, g20*Q0); pz21 = fmaf(g22, Q2, pz21);
        float pz31 = fmaf(g31, Q1, g30*Q0); pz31 = fmaf(g32, Q2, pz31);
        pz31 = fmaf(g33, Q3, pz31);

        // ===== gain: K = pz' * (S')^-1 is the TRUE gain =====
        float sg00 = s00 + RSG, sg11 = s11 + RSG;
        float det  = fmaf(sg00, sg11, -(s01*s01));
        float idet = frcp(det);
        float i00 = sg11*idet, i01 = -(s01*idet), i11 = sg00*idet;
        float K00 = fmaf(pz01,i01, pz00*i00), K01 = fmaf(pz01,i11, pz00*i01);
        float K10 = fmaf(pz11,i01, pz10*i00), K11 = fmaf(pz11,i11, pz10*i01);
        float K20 = fmaf(pz21,i01, pz20*i00), K21 = fmaf(pz21,i11, pz20*i01);
        float K30 = fmaf(pz31,i01, pz30*i00), K31 = fmaf(pz31,i11, pz30*i01);

        float nu0 = yv0 - yp0, nu1 = yv1 - yp1;
        z0v = fmaf(K00,nu0, fmaf(K01,nu1, X00));
        z1v = fmaf(K10,nu0, fmaf(K11,nu1, zp1));
        z2v = fmaf(K20,nu0, fmaf(K21,nu1, z2v));
        z3v = fmaf(K30,nu0, fmaf(K31,nu1, z3v));

        // ===== Pc_post = B' - K*pz'^T  (JIT/Q folded into B' consts) =====
        P00 = fmaf(-K00,pz00, fmaf(-K01,pz01, B00p));
        P01 = fmaf(-K00,pz10, fmaf(-K01,pz11, B01p));
        P02 = fmaf(-K00,pz20, fmaf(-K01,pz21, B02p));
        P03 = fmaf(-K00,pz30, fmaf(-K01,pz31, B03p));
        P11 = fmaf(-K10,pz10, fmaf(-K11,pz11, B11p));
        P12 = fmaf(-K10,pz20, fmaf(-K11,pz21, B12p));
        P13 = fmaf(-K10,pz30, fmaf(-K11,pz31, B13p));
        P22 = fmaf(-K20,pz20, fmaf(-K21,pz21, B22p));
        P23 = fmaf(-K20,pz30, fmaf(-K21,pz31, B23p));
        P33 = fmaf(-K30,pz30, fmaf(-K31,pz31, B33p));
    };

    // ---- prefetch ----
    float2 ycur  = *reinterpret_cast<const float2*>(yb);
    float2 ynext = *reinterpret_cast<const float2*>(yb + 2);
    float  unext = ub[0];

    // ================= t = 0 (no dynamics; B' = Pc + postJIT on diag) =================
    chol();
    update(z0v, z1v, z1v+g10, z1v-g10,
           g10, 0.0f,
           g00, 0.0f, g11, 0.0f, 0.0f,
           P00+CJ, P01, P02, P03, P11+CJ, P12, P13, P22+CJ, P23, P33+CJ,
           ycur.x, ycur.y);
    *reinterpret_cast<float4*>(ob) = make_float4(z0v, z1v, z2v, z3v);

    // ================= main loop t = 1..255 =================
    #pragma unroll 1
    for (int t = 1; t < TT; ++t) {
        float yv0 = ynext.x, yv1 = ynext.y;
        float uu  = unext;
        int tn = (t+1 < TT) ? (t+1) : (TT-1);
        ynext = *reinterpret_cast<const float2*>(yb + 2*tn);
        unext = ub[t];

        chol();

        // center dynamics
        float w  = z0v*z0v;
        float zc = w*z0v;                       // p^3 at center
        float X00 = fmaf(DT, z1v, z0v);
        float ac = fmaf(-CD, z1v, uu);
        ac = fmaf(-z2v, z0v, ac);
        ac = fmaf(-z3v, zc, ac);
        float X01 = fmaf(DT, ac, z1v);

        // col0 explicit propagation (comp1 nonlinear)
        float pp = z0v+g00, pm = z0v-g00;
        float vp = z1v+g10, vm = z1v-g10;
        float kp = z2v+g20, km = z2v-g20;
        float aap = z3v+g30, aam = z3v-g30;
        float cp3 = (pp*pp)*pp, cm3 = (pm*pm)*pm;
        float accp = fmaf(-CD, vp, uu); accp = fmaf(-kp,pp,accp); accp = fmaf(-aap,cp3,accp);
        float Xp = fmaf(DT, accp, vp);
        float accm = fmaf(-CD, vm, uu); accm = fmaf(-km,pm,accm); accm = fmaf(-aam,cm3,accm);
        float Xm = fmaf(DT, accm, vm);
        float D10 = 0.5f*(Xp - Xm);
        float q   = fmaf(0.5f, Xp + Xm, -X01);

        // odd propagation closed forms
        float D00 = fmaf(DT, g10, g00);
        float D01 = DT*g11;
        float ha  = fmaf(g31, zc, g21*z0v);
        float D11 = fmaf(CVV, g11, -(DT*ha));
        float hb  = fmaf(g32, zc, g22*z0v);
        float D12 = -(DT*hb);
        float D13 = -(DT*(g33*zc));

        // B' = CUT*P_pred (+ folded consts); CUT*W2 == 1
        float B00p = fmaf(D01,D01, fmaf(D00,D00, CB00));
        float B01p = fmaf(D01, D11, D00*D10);
        float B02p = fmaf(D01, g21, D00*g20);
        float B03p = fmaf(D01, g31, D00*g30);
        float TB11 = fmaf(D10,D10, CB11);
        TB11 = fmaf(D11,D11,TB11); TB11 = fmaf(D12,D12,TB11); TB11 = fmaf(D13,D13,TB11);
        float B11p = fmaf(CQ2C, q*q, TB11);
        float B12p = fmaf(D11,g21, D10*g20); B12p = fmaf(D12,g22,B12p);
        float B13p = fmaf(D11,g31, D10*g30); B13p = fmaf(D12,g32,B13p);
        B13p = fmaf(D13,g33,B13p);
        float B22p = P22 + CB22;
        float B23p = P23;
        float B33p = P33 + CB22;

        update(X00, X01, Xp, Xm, D10, q, D00, D01, D11, D12, D13,
               B00p,B01p,B02p,B03p,B11p,B12p,B13p,B22p,B23p,B33p, yv0, yv1);

        *reinterpret_cast<float4*>(ob + 4*t) = make_float4(z0v, z1v, z2v, z3v);
    }
}

extern "C" void kernel_launch(void* const* d_in, const int* in_sizes, int n_in,
                              void* d_out, int out_size, void* d_ws, size_t ws_size,
                              hipStream_t stream) {
    const float* y  = (const float*)d_in[0];   // (B,T,NY)
    const float* u  = (const float*)d_in[1];   // (B,T)
    const float* z0 = (const float*)d_in[2];   // (B,N)
    const float* P0 = (const float*)d_in[3];   // (B,N,N)
    float* out = (float*)d_out;                // (B,T,N)

    ukf_kernel<<<dim3(BB/64), dim3(64), 0, stream>>>(y, u, z0, P0, out);
}